// Round 12
// baseline (189.023 us; speedup 1.0000x reference)
//
#include <hip/hip_runtime.h>

// LocalCAN: S=200, B=1024, H=128, W=3, fp32.
// out[s,b,:] = sum_w x[s+w,b,:] * softmax_w( sum_h sigmoid(x[s+w,b,h]) * k[w,h] )
// x = inputs * mask[:,:,None], zero-padded past s=S-1 (pad rows contribute
// alpha = 0.5*sum(k[w]) via sigmoid(0)=0.5 — computed, not skipped).
//
// R9 = R8 with the nontemporal store fixed (native clang vector type; HIP's
// float4 is a class and rejected by __builtin_nontemporal_store).
// R8 design: wave = 2 b x 32 h-lanes, R_STRIP=8 (read amp 10/8=1.25x).
// 32-lane allreduce via 4 full-rate DPP adds (xor1,2,7,15) + ds_swizzle xor16.
// Output via nontemporal stores to keep x resident in L2/L3.

#define S_DIM 200
#define B_DIM 1024
#define H_DIM 128
#define R_STRIP 8
#define ROWS (R_STRIP + 2)           // 10 rows loaded per strip
#define BGRPS (B_DIM / 2)            // 512 b-groups of 2
#define STRIPS (S_DIM / R_STRIP)     // 25

typedef float f32x4 __attribute__((ext_vector_type(4)));

__device__ __forceinline__ float fast_rcp(float v) {
    return __builtin_amdgcn_rcpf(v);
}

template <int CTRL>
__device__ __forceinline__ float dppadd(float x) {
    // x + dpp_perm(x): full-rate VALU, no DS pipe, ~4cy latency
    return x + __int_as_float(__builtin_amdgcn_update_dpp(
        0, __float_as_int(x), CTRL, 0xF, 0xF, false));
}

__device__ __forceinline__ float red32(float p) {
    p = dppadd<0xB1>(p);    // quad_perm [1,0,3,2]  = xor 1
    p = dppadd<0x4E>(p);    // quad_perm [2,3,0,1]  = xor 2
    p = dppadd<0x141>(p);   // row_half_mirror      = xor 7  (adds bit 2)
    p = dppadd<0x140>(p);   // row_mirror           = xor 15 (adds bit 3)
    // xor 16 across the two DPP rows of each 32-lane half (BitMode offset)
    p += __int_as_float(__builtin_amdgcn_ds_swizzle(__float_as_int(p), 0x401F));
    return p;
}

__global__ __launch_bounds__(256) void LocalCAN_kernel(
    const float* __restrict__ x,     // [S,B,H]
    const float* __restrict__ mask,  // [S,B]
    const float* __restrict__ ker,   // [3,H]
    float* __restrict__ out)         // [S,B,H]
{
    const int wave  = (blockIdx.x * blockDim.x + threadIdx.x) >> 6;
    const int lane  = threadIdx.x & 63;
    const int bgrp  = wave % BGRPS;
    const int strip = wave / BGRPS;          // < STRIPS (grid exact)

    const int bsub = lane >> 5;              // 0..1
    const int hg   = lane & 31;              // 0..31
    const int b    = bgrp * 2 + bsub;
    const int h0   = hg * 4;                 // one float4 = lane's h-slice
    const int s0   = strip * R_STRIP;

    // conv kernel rows for this lane's h-slice (L1-hot, 1.5 KB total)
    float kr[3][4];
    #pragma unroll
    for (int w = 0; w < 3; ++w) {
        const float4 k4 = *reinterpret_cast<const float4*>(&ker[w * H_DIM + h0]);
        kr[w][0] = k4.x; kr[w][1] = k4.y; kr[w][2] = k4.z; kr[w][3] = k4.w;
    }

    // ---- load phase: all 10 rows issued up front (deep MLP) ----
    float v[ROWS][4];
    #pragma unroll
    for (int i = 0; i < ROWS; ++i) {
        const int r = s0 + i;
        if (r < S_DIM) {                     // wave-uniform; false only last strip
            const float m = mask[r * B_DIM + b];
            const float4 t = *reinterpret_cast<const float4*>(
                &x[((size_t)r * B_DIM + b) * H_DIM + h0]);
            v[i][0] = t.x * m; v[i][1] = t.y * m;
            v[i][2] = t.z * m; v[i][3] = t.w * m;
        } else {
            v[i][0] = v[i][1] = v[i][2] = v[i][3] = 0.f;
        }
    }

    // ---- dot phase: sigmoid once/element, 3 partial dots, DPP allreduce ----
    float d[ROWS][3];
    #pragma unroll
    for (int i = 0; i < ROWS; ++i) {
        float p0 = 0.f, p1 = 0.f, p2 = 0.f;
        #pragma unroll
        for (int j = 0; j < 4; ++j) {
            const float sg = fast_rcp(1.f + __expf(-v[i][j]));
            p0 += sg * kr[0][j];
            p1 += sg * kr[1][j];
            p2 += sg * kr[2][j];
        }
        d[i][0] = red32(p0);
        d[i][1] = red32(p1);
        d[i][2] = red32(p2);
    }

    // ---- output phase: 3-way softmax + weighted sum, 8 rows ----
    #pragma unroll
    for (int o = 0; o < R_STRIP; ++o) {
        const float d0 = d[o][0], d1 = d[o + 1][1], d2 = d[o + 2][2];
        const float mx = fmaxf(d0, fmaxf(d1, d2));
        const float e0 = __expf(d0 - mx);
        const float e1 = __expf(d1 - mx);
        const float e2 = __expf(d2 - mx);
        const float inv = fast_rcp(e0 + e1 + e2);
        const float a0 = e0 * inv, a1 = e1 * inv, a2 = e2 * inv;

        f32x4 ov;
        ov.x = v[o][0] * a0 + v[o + 1][0] * a1 + v[o + 2][0] * a2;
        ov.y = v[o][1] * a0 + v[o + 1][1] * a1 + v[o + 2][1] * a2;
        ov.z = v[o][2] * a0 + v[o + 1][2] * a1 + v[o + 2][2] * a2;
        ov.w = v[o][3] * a0 + v[o + 1][3] * a1 + v[o + 2][3] * a2;

        f32x4* op = reinterpret_cast<f32x4*>(
            &out[((size_t)(s0 + o) * B_DIM + b) * H_DIM + h0]);
        __builtin_nontemporal_store(ov, op);   // don't evict L3-resident x
    }
}

extern "C" void kernel_launch(void* const* d_in, const int* in_sizes, int n_in,
                              void* d_out, int out_size, void* d_ws, size_t ws_size,
                              hipStream_t stream) {
    const float* x    = (const float*)d_in[0];  // [S,B,H]
    const float* mask = (const float*)d_in[1];  // [S,B]
    const float* ker  = (const float*)d_in[2];  // [3,H]
    float* out = (float*)d_out;

    const int total_waves = BGRPS * STRIPS;     // 12800
    const int threads = 256;                    // 4 waves/block
    const int blocks = (total_waves * 64 + threads - 1) / threads;  // 3200
    LocalCAN_kernel<<<blocks, threads, 0, stream>>>(x, mask, ker, out);
}